// Round 10
// baseline (681.581 us; speedup 1.0000x reference)
//
#include <hip/hip_runtime.h>
#include <stdint.h>

typedef int v4i  __attribute__((ext_vector_type(4)));
typedef int v16i __attribute__((ext_vector_type(16)));

// ---------------------------------------------------------------------------
// async global->LDS, 16 bytes per lane. LDS dest is wave-uniform base +
// lane*16 (HW takes readfirstlane of the provided pointer), so each thread
// passes its own &lds[t*16] and lane 0 of each wave carries the wave base.
// ---------------------------------------------------------------------------
__device__ __forceinline__ void async_load16(const void* g, void* l) {
    auto gp = (const __attribute__((address_space(1))) unsigned int*)(uintptr_t)g;
    auto lp = (__attribute__((address_space(3))) unsigned int*)(unsigned int)(uintptr_t)l;
    __builtin_amdgcn_global_load_lds(gp, lp, 16, 0, 0);
}

// ---------------------------------------------------------------------------
// ws scalar slots: [0..1] uint absmax bits (x, w); floats at byte 8:
// sc[0]=s_x, sc[1]=s_w, sc[2]=1/(s_x*s_w)
// ---------------------------------------------------------------------------
__global__ void k_init(unsigned* bits) {
    if (threadIdx.x < 2) bits[threadIdx.x] = 0u;
}

// Fused absmax over both tensors: blocks [0,XB) scan x, [XB,grid) scan w.
__global__ void k_absmax2(const float4* __restrict__ x, int nx4,
                          const float4* __restrict__ w, int nw4,
                          unsigned* __restrict__ bits) {
    const int XB = 2048;
    const float4* in; int n4, b, nb; unsigned* ob;
    if (blockIdx.x < XB) { in = x; n4 = nx4; b = blockIdx.x;      nb = XB;              ob = bits;     }
    else                 { in = w; n4 = nw4; b = blockIdx.x - XB; nb = gridDim.x - XB;  ob = bits + 1; }
    float m = 0.0f;
    int stride = nb * blockDim.x;
    for (int i = b * blockDim.x + threadIdx.x; i < n4; i += stride) {
        float4 v = in[i];
        m = fmaxf(m, fmaxf(fmaxf(fabsf(v.x), fabsf(v.y)),
                           fmaxf(fabsf(v.z), fabsf(v.w))));
    }
    #pragma unroll
    for (int off = 32; off > 0; off >>= 1)
        m = fmaxf(m, __shfl_down(m, off, 64));
    __shared__ float red[4];
    int lane = threadIdx.x & 63, wv = threadIdx.x >> 6;
    if (lane == 0) red[wv] = m;
    __syncthreads();
    if (threadIdx.x == 0) {
        m = fmaxf(fmaxf(red[0], red[1]), fmaxf(red[2], red[3]));
        // |x| >= 0: IEEE bit pattern of non-negative floats is order-preserving
        atomicMax(ob, __float_as_uint(m));
    }
}

__global__ void k_scales(const unsigned* __restrict__ bits, float* __restrict__ sc) {
    float s[2];
    for (int i = 0; i < 2; ++i) {
        float m = __uint_as_float(bits[i]);
        int ex = 0;
        if (m > 0.0f) {
            int e;
            float f = frexpf(m, &e);      // m = f * 2^e, f in [0.5, 1)
            ex = (f == 0.5f) ? (e - 1) : e;  // exact ceil(log2(m))
        }
        s[i] = ldexpf(1.0f, 7 - ex);       // 2^(8 - ex - 1)
    }
    sc[0] = s[0];
    sc[1] = s[1];
    sc[2] = 1.0f / (s[0] * s[1]);          // powers of two: exact
}

// Fused quant of both tensors. round-half-even (rintf) == jnp.round;
// clip AFTER round, matching reference.
__global__ void k_quant2(const float4* __restrict__ x, int* __restrict__ qx, int nx4,
                         const float4* __restrict__ w, int* __restrict__ qw, int nw4,
                         const float* __restrict__ scp) {
    const int XB = 4096;
    const float4* in; int* out; int n4, b, nb; float s;
    if (blockIdx.x < XB) { in = x; out = qx; n4 = nx4; b = blockIdx.x;      nb = XB;             s = scp[0]; }
    else                 { in = w; out = qw; n4 = nw4; b = blockIdx.x - XB; nb = gridDim.x - XB; s = scp[1]; }
    int stride = nb * blockDim.x;
    for (int i = b * blockDim.x + threadIdx.x; i < n4; i += stride) {
        float4 v = in[i];
        int qa = (int)rintf(v.x * s); qa = qa > 127 ? 127 : (qa < -127 ? -127 : qa);
        int qb = (int)rintf(v.y * s); qb = qb > 127 ? 127 : (qb < -127 ? -127 : qb);
        int qc = (int)rintf(v.z * s); qc = qc > 127 ? 127 : (qc < -127 ? -127 : qc);
        int qd = (int)rintf(v.w * s); qd = qd > 127 ? 127 : (qd < -127 ? -127 : qd);
        out[i] = (qa & 0xff) | ((qb & 0xff) << 8) | ((qc & 0xff) << 16) | (qd << 24);
    }
}

// ---------------------------------------------------------------------------
// int8 NT GEMM, fine-interleaved counted-vmcnt schedule (T3+T4+T5).
// BYTE-IDENTICAL to the round-7 574.4us kernel. See round-7 comments for
// the full schedule/race audit. This round is an INSTRUMENTATION round:
// kernel_launch fires k_gemm TWICE (idempotent; identical output bytes) so
// that dur_us - 574.4 measures the gemm duration directly -- the harness
// fill dispatches crowd out per-kernel rows in the top-5 counter view.
// ---------------------------------------------------------------------------
#define GBAR()  __builtin_amdgcn_s_barrier()
#define WAITV4() asm volatile("s_waitcnt vmcnt(4)" ::: "memory")
#define WAITV0() asm volatile("s_waitcnt vmcnt(0)" ::: "memory")
#define CFENCE() asm volatile("" ::: "memory")

__global__ __launch_bounds__(512, 2) void k_gemm(const signed char* __restrict__ A,
                                                 const signed char* __restrict__ B,
                                                 float* __restrict__ out,
                                                 const float* __restrict__ scp) {
    __shared__ __align__(16) signed char lds[3 * 32768];  // 3 x (A 16K + B 16K)
    const int tid  = threadIdx.x;
    const int lane = tid & 63;
    const int wave = tid >> 6;
    const int wm   = wave >> 2;         // 0..1
    const int wn   = wave & 3;          // 0..3
    const int l31  = lane & 31;
    const int lhi  = lane >> 5;

    // T1: XCD-bijective swizzle, nwg=1024 (%8==0).
    const int orig = blockIdx.x;
    const int v    = (orig & 7) * 128 + (orig >> 3);
    const int n0   = (v & 3) * 256;
    const int m0   = (v >> 2) * 256;

    v16i acc[4][2];
    #pragma unroll
    for (int a = 0; a < 4; ++a)
        #pragma unroll
        for (int b = 0; b < 2; ++b)
            #pragma unroll
            for (int i = 0; i < 16; ++i) acc[a][b][i] = 0;

    // Staging map: chunk i = s*512+tid -> physical row p=i>>2, slot q=i&3;
    // source slot = q ^ ((p>>1)&3) (T2 involution on global side, rule #21).
    const signed char* gA[2];
    const signed char* gB[2];
    #pragma unroll
    for (int s = 0; s < 2; ++s) {
        int i = s * 512 + tid;
        int p = i >> 2;
        int q = (i & 3) ^ ((p >> 1) & 3);
        gA[s] = A + (size_t)(m0 + p) * 1024 + q * 16;
        gB[s] = B + (size_t)(n0 + p) * 1024 + q * 16;
    }

    auto STAGE_PIECE = [&](signed char* base, int k0, int j) {
        int s = j >> 1;
        if ((j & 1) == 0) async_load16(gA[s] + k0, base +         s * 8192 + tid * 16);
        else              async_load16(gB[s] + k0, base + 16384 + s * 8192 + tid * 16);
    };

    // prologue: tiles 0 and 1 fully staged (8 loads/thread in flight)
    {
        signed char* b0 = lds;
        signed char* b1 = lds + 32768;
        #pragma unroll
        for (int j = 0; j < 4; ++j) STAGE_PIECE(b0, 0, j);
        #pragma unroll
        for (int j = 0; j < 4; ++j) STAGE_PIECE(b1, 64, j);
    }

    const int key = (l31 >> 1) & 3;     // per-lane constant swizzle key

    signed char* rd  = lds;             // tile t
    signed char* mid = lds + 32768;     // tile t+1 (landing)
    signed char* st  = lds + 65536;     // tile t+2 (stage target)

    #pragma unroll
    for (int t = 0; t < 16; ++t) {
        if (t == 15) { WAITV0(); } else { WAITV4(); }   // own tile-t loads done
        GBAR();                                          // => ALL waves' done
        CFENCE();                                        // no ds_read hoisting
        const signed char* Ab = rd;
        const signed char* Bb = rd + 16384;
        const int k2 = (t + 2) * 64;
        const bool dostage = (t < 14);
        #pragma unroll
        for (int ks = 0; ks < 2; ++ks) {
            const int slot = ((ks * 2 + lhi) ^ key) * 16;
            v4i bf0 = *(const v4i*)(Bb + (wn * 64 +      l31) * 64 + slot);
            v4i bf1 = *(const v4i*)(Bb + (wn * 64 + 32 + l31) * 64 + slot);
            #pragma unroll
            for (int h = 0; h < 2; ++h) {
                v4i a0 = *(const v4i*)(Ab + (wm * 128 + (h * 2    ) * 32 + l31) * 64 + slot);
                v4i a1 = *(const v4i*)(Ab + (wm * 128 + (h * 2 + 1) * 32 + l31) * 64 + slot);
                if (dostage) STAGE_PIECE(st, k2, ks * 2 + h);   // 1 load/phase
                __builtin_amdgcn_s_setprio(1);
                acc[h*2  ][0] = __builtin_amdgcn_mfma_i32_32x32x32_i8(a0, bf0, acc[h*2  ][0], 0, 0, 0);
                acc[h*2  ][1] = __builtin_amdgcn_mfma_i32_32x32x32_i8(a0, bf1, acc[h*2  ][1], 0, 0, 0);
                acc[h*2+1][0] = __builtin_amdgcn_mfma_i32_32x32x32_i8(a1, bf0, acc[h*2+1][0], 0, 0, 0);
                acc[h*2+1][1] = __builtin_amdgcn_mfma_i32_32x32x32_i8(a1, bf1, acc[h*2+1][1], 0, 0, 0);
                __builtin_amdgcn_s_setprio(0);
            }
        }
        // rotate buffers (constant-folded by full unroll)
        signed char* tmp = rd; rd = mid; mid = st; st = tmp;
    }

    const float inv = scp[0];
    #pragma unroll
    for (int tm = 0; tm < 4; ++tm)
        #pragma unroll
        for (int tn = 0; tn < 2; ++tn)
            #pragma unroll
            for (int r = 0; r < 16; ++r) {
                int row = m0 + wm * 128 + tm * 32 + (r & 3) + 8 * (r >> 2) + 4 * lhi;
                int col = n0 + wn * 64 + tn * 32 + l31;
                out[(size_t)row * 1024 + col] = (float)acc[tm][tn][r] * inv;
            }
}

// ---------------------------------------------------------------------------
extern "C" void kernel_launch(void* const* d_in, const int* in_sizes, int n_in,
                              void* d_out, int out_size, void* d_ws, size_t ws_size,
                              hipStream_t stream) {
    const float* x = (const float*)d_in[0];   // [65536,1024]
    const float* w = (const float*)d_in[1];   // [1024,1024]
    // d_in[2] (bias) is unused by the reference
    float* out = (float*)d_out;               // [65536,1024] fp32

    const int NX = 65536 * 1024;              // x elements
    const int NW = 1024 * 1024;               // w elements

    char* ws = (char*)d_ws;
    unsigned* bits = (unsigned*)ws;           // 2 uints
    float* sc = (float*)(ws + 8);             // 3 floats
    signed char* qx = (signed char*)(ws + 256);
    signed char* qw = qx + (size_t)NX;        // + 64 MB

    k_init<<<1, 64, 0, stream>>>(bits);
    // fused absmax: 2048 x-blocks + 128 w-blocks
    k_absmax2<<<2048 + 128, 256, 0, stream>>>((const float4*)x, NX / 4,
                                              (const float4*)w, NW / 4, bits);
    k_scales<<<1, 1, 0, stream>>>(bits, sc);
    // fused quant: 4096 x-blocks + 128 w-blocks
    k_quant2<<<4096 + 128, 256, 0, stream>>>((const float4*)x, (int*)qx, NX / 4,
                                             (const float4*)w, (int*)qw, NW / 4, sc);

    // INSTRUMENTATION: k_gemm launched twice (idempotent -- identical bytes
    // rewritten). dur_us minus round-7's 574.4 measures gemm duration,
    // which the fill-dominated top-5 counter view cannot show. Remove the
    // duplicate next round.
    k_gemm<<<dim3(1024), 512, 0, stream>>>(qx, qw, out, sc + 2);
    k_gemm<<<dim3(1024), 512, 0, stream>>>(qx, qw, out, sc + 2);
}

// Round 12
// 579.632 us; speedup vs baseline: 1.1759x; 1.1759x over previous
//
#include <hip/hip_runtime.h>
#include <stdint.h>

typedef int v4i  __attribute__((ext_vector_type(4)));
typedef int v16i __attribute__((ext_vector_type(16)));

// ---------------------------------------------------------------------------
// async global->LDS, 16 bytes per lane. LDS dest is wave-uniform base +
// lane*16 (HW takes readfirstlane of the provided pointer), so each thread
// passes its own &lds[t*16] and lane 0 of each wave carries the wave base.
// ---------------------------------------------------------------------------
__device__ __forceinline__ void async_load16(const void* g, void* l) {
    auto gp = (const __attribute__((address_space(1))) unsigned int*)(uintptr_t)g;
    auto lp = (__attribute__((address_space(3))) unsigned int*)(unsigned int)(uintptr_t)l;
    __builtin_amdgcn_global_load_lds(gp, lp, 16, 0, 0);
}

// ---------------------------------------------------------------------------
// ws scalar slots: [0..1] uint absmax bits (x, w); floats at byte 8:
// sc[0]=s_x, sc[1]=s_w, sc[2]=1/(s_x*s_w)
// ---------------------------------------------------------------------------
__global__ void k_init(unsigned* bits) {
    if (threadIdx.x < 2) bits[threadIdx.x] = 0u;
}

// Fused absmax over both tensors: blocks [0,XB) scan x, [XB,grid) scan w.
__global__ void k_absmax2(const float4* __restrict__ x, int nx4,
                          const float4* __restrict__ w, int nw4,
                          unsigned* __restrict__ bits) {
    const int XB = 2048;
    const float4* in; int n4, b, nb; unsigned* ob;
    if (blockIdx.x < XB) { in = x; n4 = nx4; b = blockIdx.x;      nb = XB;              ob = bits;     }
    else                 { in = w; n4 = nw4; b = blockIdx.x - XB; nb = gridDim.x - XB;  ob = bits + 1; }
    float m = 0.0f;
    int stride = nb * blockDim.x;
    for (int i = b * blockDim.x + threadIdx.x; i < n4; i += stride) {
        float4 v = in[i];
        m = fmaxf(m, fmaxf(fmaxf(fabsf(v.x), fabsf(v.y)),
                           fmaxf(fabsf(v.z), fabsf(v.w))));
    }
    #pragma unroll
    for (int off = 32; off > 0; off >>= 1)
        m = fmaxf(m, __shfl_down(m, off, 64));
    __shared__ float red[4];
    int lane = threadIdx.x & 63, wv = threadIdx.x >> 6;
    if (lane == 0) red[wv] = m;
    __syncthreads();
    if (threadIdx.x == 0) {
        m = fmaxf(fmaxf(red[0], red[1]), fmaxf(red[2], red[3]));
        // |x| >= 0: IEEE bit pattern of non-negative floats is order-preserving
        atomicMax(ob, __float_as_uint(m));
    }
}

__global__ void k_scales(const unsigned* __restrict__ bits, float* __restrict__ sc) {
    float s[2];
    for (int i = 0; i < 2; ++i) {
        float m = __uint_as_float(bits[i]);
        int ex = 0;
        if (m > 0.0f) {
            int e;
            float f = frexpf(m, &e);      // m = f * 2^e, f in [0.5, 1)
            ex = (f == 0.5f) ? (e - 1) : e;  // exact ceil(log2(m))
        }
        s[i] = ldexpf(1.0f, 7 - ex);       // 2^(8 - ex - 1)
    }
    sc[0] = s[0];
    sc[1] = s[1];
    sc[2] = 1.0f / (s[0] * s[1]);          // powers of two: exact
}

// Fused quant of both tensors. round-half-even (rintf) == jnp.round;
// clip AFTER round, matching reference.
__global__ void k_quant2(const float4* __restrict__ x, int* __restrict__ qx, int nx4,
                         const float4* __restrict__ w, int* __restrict__ qw, int nw4,
                         const float* __restrict__ scp) {
    const int XB = 4096;
    const float4* in; int* out; int n4, b, nb; float s;
    if (blockIdx.x < XB) { in = x; out = qx; n4 = nx4; b = blockIdx.x;      nb = XB;             s = scp[0]; }
    else                 { in = w; out = qw; n4 = nw4; b = blockIdx.x - XB; nb = gridDim.x - XB; s = scp[1]; }
    int stride = nb * blockDim.x;
    for (int i = b * blockDim.x + threadIdx.x; i < n4; i += stride) {
        float4 v = in[i];
        int qa = (int)rintf(v.x * s); qa = qa > 127 ? 127 : (qa < -127 ? -127 : qa);
        int qb = (int)rintf(v.y * s); qb = qb > 127 ? 127 : (qb < -127 ? -127 : qb);
        int qc = (int)rintf(v.z * s); qc = qc > 127 ? 127 : (qc < -127 ? -127 : qc);
        int qd = (int)rintf(v.w * s); qd = qd > 127 ? 127 : (qd < -127 ? -127 : qd);
        out[i] = (qa & 0xff) | ((qb & 0xff) << 8) | ((qc & 0xff) << 16) | (qd << 24);
    }
}

// ---------------------------------------------------------------------------
// int8 NT GEMM, fine-interleaved counted-vmcnt schedule (T3+T4+T5).
// MEASURED (r10 double-launch): the round-7 256^2 8-wave version of this
// schedule = 107 us, ~29% MfmaUtil, at 2 waves/SIMD (one 512-thread block;
// 96KB LDS + ~200 VGPR block a second). Stall analysis: vmcnt waits are
// cold (loads issued a full tile early), so the ~60%/tile stall is
// lgkmcnt-on-ds_read + barrier skew, poorly hidden at 2 waves/SIMD.
//
// THIS ROUND: occupancy 2 -> 4 waves/SIMD via TWO INDEPENDENT blocks/CU.
// Tile 128x256, 8 waves of 64x64 (acc[2][2] = 64 VGPR), LDS 3 x 24KB = 72KB
// (2 x 72 = 144 <= 160), __launch_bounds__(512,4) caps VGPR at 128.
// Independent blocks overlap each other's barrier/lgkm stalls (m114).
// Schedule per K-tile (BK=64, 16 tiles) unchanged from round 7:
//   entry: wait own vmcnt(3) [tile t landed; t+1's 3 still in flight]
//   -> s_barrier -> 4 phases of {ds_read x2-3, issue 1 of 3 stage pieces
//   for tile t+2 into the 3rd buffer, setprio(1), 2 MFMA, setprio(0)}.
//   Never vmcnt(0) until the last tile (T4).
// T2 swizzle (64B rows): physical 16B slot q of row p holds logical
// q^((p>>1)&3); involution applied on the GLOBAL source slot (staging,
// rule #21) and on the ds_read addr. Row bases are multiples of 32 so the
// read key (l31>>1)&3 is per-lane constant. 4 hits/bank per 32-lane phase.
// Fragment layouts (harness-verified r5-r10):
//   A: lane holds A[m = lane&31][k = ks*32 + (lane>>5)*16 + j], j=0..15
//   B: lane holds B[n = lane&31][same k slice]
//   C/D: col = lane&31, row = (reg&3) + 8*(reg>>2) + 4*(lane>>5)
// Race audit: stage targets the buffer last read at t-1; entry barrier of
// tile t proves all waves left t-1; per-thread load order is
// oldest-tile-first so vmcnt(3) == "tile t landed".
// ---------------------------------------------------------------------------
#define GBAR()  __builtin_amdgcn_s_barrier()
#define WAITV3() asm volatile("s_waitcnt vmcnt(3)" ::: "memory")
#define WAITV0() asm volatile("s_waitcnt vmcnt(0)" ::: "memory")
#define CFENCE() asm volatile("" ::: "memory")

__global__ __launch_bounds__(512, 4) void k_gemm(const signed char* __restrict__ A,
                                                 const signed char* __restrict__ B,
                                                 float* __restrict__ out,
                                                 const float* __restrict__ scp) {
    __shared__ __align__(16) signed char lds[3 * 24576];  // 3 x (A 8K + B 16K)
    const int tid  = threadIdx.x;
    const int lane = tid & 63;
    const int wave = tid >> 6;
    const int wm   = wave >> 2;         // 0..1  (m-half of 128)
    const int wn   = wave & 3;          // 0..3  (n-quarter of 256)
    const int l31  = lane & 31;
    const int lhi  = lane >> 5;

    // T1: XCD-bijective swizzle, nwg=2048 (%8==0). XCD j gets virtual range
    // [j*256,(j+1)*256): n fast (4), m slow -> B (1MB) L2-resident, A-panels
    // reused 4x within one XCD's L2.
    const int orig = blockIdx.x;
    const int v    = (orig & 7) * 256 + (orig >> 3);
    const int n0   = (v & 3) * 256;
    const int m0   = (v >> 2) * 128;

    v16i acc[2][2];
    #pragma unroll
    for (int a = 0; a < 2; ++a)
        #pragma unroll
        for (int b = 0; b < 2; ++b)
            #pragma unroll
            for (int i = 0; i < 16; ++i) acc[a][b][i] = 0;

    // Staging map. A tile = 128 rows x 4 slots = 512 chunks = 1/thread;
    // B tile = 256 rows x 4 slots = 1024 chunks = 2/thread.
    // Chunk i -> physical row p=i>>2, slot q=i&3; source slot q^((p>>1)&3).
    const signed char* gA;
    {
        int p = tid >> 2;
        int q = (tid & 3) ^ ((p >> 1) & 3);
        gA = A + (size_t)(m0 + p) * 1024 + q * 16;
    }
    const signed char* gB[2];
    #pragma unroll
    for (int s = 0; s < 2; ++s) {
        int i = s * 512 + tid;
        int p = i >> 2;
        int q = (i & 3) ^ ((p >> 1) & 3);
        gB[s] = B + (size_t)(n0 + p) * 1024 + q * 16;
    }

    // 3 stage pieces per K-tile: j=0 -> A, j=1 -> B shot0, j=2 -> B shot1.
    auto STAGE_PIECE = [&](signed char* base, int k0, int j) {
        if (j == 0)      async_load16(gA + k0,    base +          tid * 16);
        else if (j == 1) async_load16(gB[0] + k0, base +  8192 +  tid * 16);
        else             async_load16(gB[1] + k0, base + 16384 +  tid * 16);
    };

    // prologue: tiles 0 and 1 fully staged (6 loads/thread in flight)
    #pragma unroll
    for (int j = 0; j < 3; ++j) STAGE_PIECE(lds, 0, j);
    #pragma unroll
    for (int j = 0; j < 3; ++j) STAGE_PIECE(lds + 24576, 64, j);

    const int key = (l31 >> 1) & 3;     // per-lane constant swizzle key

    signed char* rd  = lds;             // tile t
    signed char* mid = lds + 24576;     // tile t+1 (landing)
    signed char* st  = lds + 49152;     // tile t+2 (stage target)

    #pragma unroll
    for (int t = 0; t < 16; ++t) {
        if (t == 15) { WAITV0(); } else { WAITV3(); }   // own tile-t loads done
        GBAR();                                          // => ALL waves' done
        CFENCE();                                        // no ds_read hoisting
        const signed char* Ab = rd;
        const signed char* Bb = rd + 8192;
        const int k2 = (t + 2) * 64;
        const bool dostage = (t < 14);
        #pragma unroll
        for (int ks = 0; ks < 2; ++ks) {
            const int slot = ((ks * 2 + lhi) ^ key) * 16;
            v4i bf0 = *(const v4i*)(Bb + (wn * 64 +      l31) * 64 + slot);
            v4i bf1 = *(const v4i*)(Bb + (wn * 64 + 32 + l31) * 64 + slot);
            #pragma unroll
            for (int h = 0; h < 2; ++h) {
                v4i a = *(const v4i*)(Ab + (wm * 64 + h * 32 + l31) * 64 + slot);
                if (dostage && (ks * 2 + h) < 3) STAGE_PIECE(st, k2, ks * 2 + h);
                __builtin_amdgcn_s_setprio(1);
                acc[h][0] = __builtin_amdgcn_mfma_i32_32x32x32_i8(a, bf0, acc[h][0], 0, 0, 0);
                acc[h][1] = __builtin_amdgcn_mfma_i32_32x32x32_i8(a, bf1, acc[h][1], 0, 0, 0);
                __builtin_amdgcn_s_setprio(0);
            }
        }
        // rotate buffers (constant-folded by full unroll)
        signed char* tmp = rd; rd = mid; mid = st; st = tmp;
    }

    const float inv = scp[0];
    #pragma unroll
    for (int tm = 0; tm < 2; ++tm)
        #pragma unroll
        for (int tn = 0; tn < 2; ++tn)
            #pragma unroll
            for (int r = 0; r < 16; ++r) {
                int row = m0 + wm * 64 + tm * 32 + (r & 3) + 8 * (r >> 2) + 4 * lhi;
                int col = n0 + wn * 64 + tn * 32 + l31;
                out[(size_t)row * 1024 + col] = (float)acc[tm][tn][r] * inv;
            }
}

// ---------------------------------------------------------------------------
extern "C" void kernel_launch(void* const* d_in, const int* in_sizes, int n_in,
                              void* d_out, int out_size, void* d_ws, size_t ws_size,
                              hipStream_t stream) {
    const float* x = (const float*)d_in[0];   // [65536,1024]
    const float* w = (const float*)d_in[1];   // [1024,1024]
    // d_in[2] (bias) is unused by the reference
    float* out = (float*)d_out;               // [65536,1024] fp32

    const int NX = 65536 * 1024;              // x elements
    const int NW = 1024 * 1024;               // w elements

    char* ws = (char*)d_ws;
    unsigned* bits = (unsigned*)ws;           // 2 uints
    float* sc = (float*)(ws + 8);             // 3 floats
    signed char* qx = (signed char*)(ws + 256);
    signed char* qw = qx + (size_t)NX;        // + 64 MB

    k_init<<<1, 64, 0, stream>>>(bits);
    // fused absmax: 2048 x-blocks + 128 w-blocks
    k_absmax2<<<2048 + 128, 256, 0, stream>>>((const float4*)x, NX / 4,
                                              (const float4*)w, NW / 4, bits);
    k_scales<<<1, 1, 0, stream>>>(bits, sc);
    // fused quant: 4096 x-blocks + 128 w-blocks
    k_quant2<<<4096 + 128, 256, 0, stream>>>((const float4*)x, (int*)qx, NX / 4,
                                             (const float4*)w, (int*)qw, NW / 4, sc);

    // 128x256 tiles: grid = 512 m x 4 n = 2048 blocks, 2 blocks/CU resident
    k_gemm<<<dim3(2048), 512, 0, stream>>>(qx, qw, out, sc + 2);
}